// Round 1
// 868.545 us; speedup vs baseline: 1.0534x; 1.0534x over previous
//
#include <hip/hip_runtime.h>

#define MUL 32
#define N_NODES 50000
#define N_EDGES 800000
#define ROW_OUT 352   // 11*MUL
#define ROW_X 128     // 4*MUL
#define ROW_W 160     // 5*MUL

#define INV_SQRT3 0.57735026918962576f
#define INV_SQRT2 0.70710678118654752f

#define SCAN_THREADS 1024

// ---------------- Phase 1: histogram of edge_dst ----------------
__global__ __launch_bounds__(256) void hist_kernel(
    const int* __restrict__ edge_dst, int* __restrict__ counts)
{
    int e = blockIdx.x * blockDim.x + threadIdx.x;
    if (e < N_EDGES) atomicAdd(&counts[edge_dst[e]], 1);
}

// ---------------- Phase 2: exclusive scan (single block, shfl-based) ----------------
// Old version: Hillis-Steele over LDS, 10 barrier-steps x 49 chunks on one CU.
// New: 6-step __shfl_up wave scan + 16-entry wave-sum scan, 3 barriers/chunk,
// next chunk's loads prefetched across the barriers.
__global__ __launch_bounds__(SCAN_THREADS) void scan_kernel(
    const int* __restrict__ counts, int* __restrict__ offsets,
    int* __restrict__ cursor)
{
    __shared__ int wsum[16];
    __shared__ int wexcl[16];
    __shared__ int blocktot;

    const int t = threadIdx.x;
    const int w = t >> 6;
    const int lane = t & 63;

    int carry = 0;
    int v = (t < N_NODES) ? counts[t] : 0;

    for (int base = 0; base < N_NODES; base += SCAN_THREADS) {
        // prefetch next chunk (overlaps the barriers below)
        const int inext = base + SCAN_THREADS + t;
        int vnext = (inext < N_NODES) ? counts[inext] : 0;

        // inclusive wave scan via shfl_up (no barriers)
        int s = v;
        #pragma unroll
        for (int off = 1; off < 64; off <<= 1) {
            int y = __shfl_up(s, off);
            if (lane >= off) s += y;
        }
        if (lane == 63) wsum[w] = s;
        __syncthreads();

        // wave 0 scans the 16 wave-sums
        if (t < 16) {
            int ws_ = wsum[t];
            int ss = ws_;
            #pragma unroll
            for (int off = 1; off < 16; off <<= 1) {
                int y = __shfl_up(ss, off);
                if (t >= off) ss += y;
            }
            wexcl[t] = ss - ws_;
            if (t == 15) blocktot = ss;
        }
        __syncthreads();

        const int excl = s - v + wexcl[w] + carry;
        const int i = base + t;
        if (i < N_NODES) { offsets[i] = excl; cursor[i] = excl; }
        carry += blocktot;
        v = vnext;
        __syncthreads();   // protect wsum/wexcl/blocktot before next chunk
    }
}

// ---------------- Phase 3: fill CSR with fused (edge_id, src) pairs ----------------
// Storing src alongside e removes one dependent-load level from the gather
// critical path (was: edge_ids[p] -> edge_src[e] -> x[src]).
__global__ __launch_bounds__(256) void fill_kernel(
    const int* __restrict__ edge_dst, const int* __restrict__ edge_src,
    int* __restrict__ cursor, int2* __restrict__ pairs)
{
    int e = blockIdx.x * blockDim.x + threadIdx.x;
    if (e < N_EDGES) {
        int p = atomicAdd(&cursor[edge_dst[e]], 1);
        pairs[p] = make_int2(e, edge_src[e]);
    }
}

// ---------------- Phase 4: gather-accumulate, one wave per node ----------------
// Wave of 64 = two half-waves; half h processes edges j = h, h+2, ...
// Lane u (0..31) owns mul-channel u. Software-pipelined 1 edge ahead:
// iteration j issues ALL loads for edge j+2 before doing edge j's math.
// edge_weight (512 MB stream, zero reuse) uses nontemporal loads so it
// doesn't evict the reused x rows (25.6 MB) from L2.
struct Ed {
    float a0, a1x, a1y, a1z;
    float w0, w1, w2, w3, w4;
    float xs0, x1x, x1y, x1z;
};

__device__ __forceinline__ Ed load_edge(
    const float* __restrict__ x,
    const float* __restrict__ edge_attr,
    const float* __restrict__ edge_weight,
    int2 p, int u)
{
    Ed d;
    const float4 a = *reinterpret_cast<const float4*>(edge_attr + (size_t)p.x * 4);
    d.a0 = a.x; d.a1x = a.y; d.a1y = a.z; d.a1z = a.w;

    const float* wrow = edge_weight + (size_t)p.x * ROW_W;
    d.w0 = __builtin_nontemporal_load(wrow + 0 * MUL + u);
    d.w1 = __builtin_nontemporal_load(wrow + 1 * MUL + u);
    d.w2 = __builtin_nontemporal_load(wrow + 2 * MUL + u);
    d.w3 = __builtin_nontemporal_load(wrow + 3 * MUL + u);
    d.w4 = __builtin_nontemporal_load(wrow + 4 * MUL + u);

    const float* xrow = x + (size_t)p.y * ROW_X;
    d.xs0 = xrow[u];
    d.x1x = xrow[MUL + u * 3 + 0];
    d.x1y = xrow[MUL + u * 3 + 1];
    d.x1z = xrow[MUL + u * 3 + 2];
    return d;
}

__global__ __launch_bounds__(256) void gather_kernel(
    const float* __restrict__ x,
    const float* __restrict__ edge_attr,
    const float* __restrict__ edge_weight,
    const int*   __restrict__ offsets,
    const int*   __restrict__ counts,
    const int2*  __restrict__ pairs,
    float*       __restrict__ out)
{
    const int wave_in_block = threadIdx.x >> 6;
    const int n = blockIdx.x * (blockDim.x >> 6) + wave_in_block;
    if (n >= N_NODES) return;

    const int lane = threadIdx.x & 63;
    const int half = lane >> 5;
    const int u = lane & 31;

    const int start = offsets[n];
    const int deg = counts[n];

    float acc0 = 0.f;
    float acc1x = 0.f, acc1y = 0.f, acc1z = 0.f;
    float acc2x = 0.f, acc2y = 0.f, acc2z = 0.f;
    float acc3 = 0.f;
    float acc4x = 0.f, acc4y = 0.f, acc4z = 0.f;

    int j = half;
    if (j < deg) {
        int2 pcur = pairs[start + j];
        int2 pnxt = (j + 2 < deg) ? pairs[start + j + 2] : pcur;
        Ed dc = load_edge(x, edge_attr, edge_weight, pcur, u);

        for (; j < deg; j += 2) {
            // prefetch pair two iterations ahead, data one iteration ahead
            int2 pfar = (j + 4 < deg) ? pairs[start + j + 4] : pnxt;
            Ed dn = load_edge(x, edge_attr, edge_weight, pnxt, u);

            // math on current edge (loads were issued last iteration)
            acc0 += dc.w0 * dc.xs0 * dc.a0;

            const float w1xs0 = dc.w1 * dc.xs0;
            acc1x += w1xs0 * dc.a1x;
            acc1y += w1xs0 * dc.a1y;
            acc1z += w1xs0 * dc.a1z;

            const float w2a0 = dc.w2 * dc.a0;
            acc2x += w2a0 * dc.x1x;
            acc2y += w2a0 * dc.x1y;
            acc2z += w2a0 * dc.x1z;

            const float dot = dc.x1x * dc.a1x + dc.x1y * dc.a1y + dc.x1z * dc.a1z;
            acc3 += dc.w3 * dot * INV_SQRT3;

            const float cx = dc.x1y * dc.a1z - dc.x1z * dc.a1y;
            const float cy = dc.x1z * dc.a1x - dc.x1x * dc.a1z;
            const float cz = dc.x1x * dc.a1y - dc.x1y * dc.a1x;
            const float w4s = dc.w4 * INV_SQRT2;
            acc4x += w4s * cx;
            acc4y += w4s * cy;
            acc4z += w4s * cz;

            dc = dn;
            pnxt = pfar;
        }
    }

    // combine the two half-waves (lanes 0..31 += lanes 32..63)
    acc0  += __shfl_down(acc0, 32);
    acc1x += __shfl_down(acc1x, 32);
    acc1y += __shfl_down(acc1y, 32);
    acc1z += __shfl_down(acc1z, 32);
    acc2x += __shfl_down(acc2x, 32);
    acc2y += __shfl_down(acc2y, 32);
    acc2z += __shfl_down(acc2z, 32);
    acc3  += __shfl_down(acc3, 32);
    acc4x += __shfl_down(acc4x, 32);
    acc4y += __shfl_down(acc4y, 32);
    acc4z += __shfl_down(acc4z, 32);

    if (half == 0) {
        float* orow = out + (size_t)n * ROW_OUT;
        orow[u] = acc0;
        orow[1 * MUL + u * 3 + 0] = acc1x;
        orow[1 * MUL + u * 3 + 1] = acc1y;
        orow[1 * MUL + u * 3 + 2] = acc1z;
        orow[4 * MUL + u * 3 + 0] = acc2x;
        orow[4 * MUL + u * 3 + 1] = acc2y;
        orow[4 * MUL + u * 3 + 2] = acc2z;
        orow[7 * MUL + u] = acc3;
        orow[8 * MUL + u * 3 + 0] = acc4x;
        orow[8 * MUL + u * 3 + 1] = acc4y;
        orow[8 * MUL + u * 3 + 2] = acc4z;
    }
}

extern "C" void kernel_launch(void* const* d_in, const int* in_sizes, int n_in,
                              void* d_out, int out_size, void* d_ws, size_t ws_size,
                              hipStream_t stream) {
    const float* x           = (const float*)d_in[0];
    const float* edge_attr   = (const float*)d_in[1];
    const float* edge_weight = (const float*)d_in[2];
    const int*   edge_dst    = (const int*)d_in[3];
    const int*   edge_src    = (const int*)d_in[4];
    float* out = (float*)d_out;

    // workspace layout (ints): counts[50000] | offsets[50000] | cursor[50000] | pairs[2*800000]
    int*  counts  = (int*)d_ws;
    int*  offsets = counts + N_NODES;
    int*  cursor  = offsets + N_NODES;
    int2* pairs   = (int2*)(cursor + N_NODES);   // byte offset 600000, 8B-aligned

    hipMemsetAsync(counts, 0, (size_t)N_NODES * sizeof(int), stream);

    const int eb = (N_EDGES + 255) / 256;
    hist_kernel<<<eb, 256, 0, stream>>>(edge_dst, counts);
    scan_kernel<<<1, SCAN_THREADS, 0, stream>>>(counts, offsets, cursor);
    fill_kernel<<<eb, 256, 0, stream>>>(edge_dst, edge_src, cursor, pairs);

    // one 64-lane wave per node, 4 waves per block
    const int waves_per_block = 4;
    const int nb = (N_NODES + waves_per_block - 1) / waves_per_block;
    gather_kernel<<<nb, waves_per_block * 64, 0, stream>>>(
        x, edge_attr, edge_weight, offsets, counts, pairs, out);
}